// Round 12
// baseline (659.003 us; speedup 1.0000x reference)
//
#include <hip/hip_runtime.h>

#define NTOK 262144
#define TT 64
#define EPS 1e-5f

typedef short short8 __attribute__((ext_vector_type(8)));
typedef float float4v __attribute__((ext_vector_type(4)));

// Packed bf16 weights: [g(4)][nt(16)][kb(8)][lane(64)][j(8)]
// element = W[kb*32 + (lane>>4)*8 + j][nt*16 + (lane&15)]
__device__ __align__(16) short g_Wp[4 * 65536];   // 512 KB static device mem
// LN-fold vectors: 0:gW1=g1@W11  1:beW1=be1@W11+b11  2:gW2=g2@W21  3:beW2=be2@W21+b21
__device__ float g_par[4 * 256];

__device__ __forceinline__ short f2bf(float f) {   // RTN f32->bf16
    uint32_t u = __builtin_bit_cast(uint32_t, f);
    u += 0x7FFFu + ((u >> 16) & 1u);
    return (short)(u >> 16);
}

__global__ void pack_w(const float* __restrict__ W11, const float* __restrict__ W12,
                       const float* __restrict__ W21, const float* __restrict__ W22) {
    int t = blockIdx.x * 256 + threadIdx.x;          // 0 .. 262143
    int g = t >> 16;
    int r = t & 65535;
    int j = r & 7, l = (r >> 3) & 63, kb = (r >> 9) & 7, nt = (r >> 12) & 15;
    int n = nt * 16 + (l & 15);
    int k = kb * 32 + (l >> 4) * 8 + j;
    const float* W = (g == 0) ? W11 : (g == 1) ? W12 : (g == 2) ? W21 : W22;
    g_Wp[t] = f2bf(W[k * 256 + n]);
}

// LN-through-GEMM fold: ln(x)@W + b = rs*((x*g)@W - mu*(g@W)) + (be@W + b).
// Precompute gW and beW once (f32, coalesced over j).
__global__ void prep_par(const float* __restrict__ g1, const float* __restrict__ be1,
                         const float* __restrict__ b11, const float* __restrict__ W11,
                         const float* __restrict__ g2, const float* __restrict__ be2,
                         const float* __restrict__ b21, const float* __restrict__ W21) {
    int j = threadIdx.x, l = blockIdx.x;             // l: 0..3
    const float* W = (l < 2) ? W11 : W21;
    const float* v = (l == 0) ? g1 : (l == 1) ? be1 : (l == 2) ? g2 : be2;
    float s = 0.f;
    for (int n = 0; n < 256; ++n) s = __builtin_fmaf(v[n], W[n * 256 + j], s);
    if (l == 1) s += b11[j];
    if (l == 3) s += b21[j];
    g_par[l * 256 + j] = s;
}

// exact-erf gelu via Abramowitz-Stegun 7.1.26 (max erf err 1.5e-7).
__device__ __forceinline__ float gelu_erf(float v) {
    float z = fabsf(v) * 0.70710678118654752f;
    float d = __builtin_fmaf(0.3275911f, z, 1.0f);
    float t;
    asm("v_rcp_f32 %0, %1" : "=v"(t) : "v"(d));
    float poly = t * (0.254829592f + t * (-0.284496736f + t * (1.421413741f
               + t * (-1.453152027f + t * 1.061405429f))));
    float er = 1.0f - poly * __expf(-z * z);
    er = copysignf(er, v);
    return 0.5f * v * (1.0f + er);
}

// A-operand packed LDS index for element (m, k), rotr2 lane-slot swizzle.
// ds_write_b16 bank = 4q + 16*(c>>3) + ((c&7)>>1): 2 lanes/bank (free, m136).
__device__ __forceinline__ int aidx(int m, int k) {
    int lp = (m & 15) | (((k >> 3) & 3) << 4);
    int gs = (lp >> 2) | ((lp & 3) << 4);
    return ((((m >> 4) * 8 + (k >> 5)) * 64) + gs) * 8 + (k & 7);
}

// Dual-tile anti-phase pipeline, LN folded through the GEMMs.
// Evidence (r3, r7): HW never co-schedules a 2nd workgroup of this kernel per
// CU regardless of LDS/VGPR headroom -> all optimization goes into shortening
// the per-block barrier chain: 13 -> 10 barriers this round.
// NOTE: do NOT force a waves/EU bound: (256,2) and (512,4) both produced
// wrong results (forced register-cap codegen). (512,1) leaves the allocator
// free and has been correct in every measured round.
__global__ __launch_bounds__(512, 1) void fused_kernel(
    const float* __restrict__ meas, const float* __restrict__ event,
    const float* __restrict__ leak, const float* __restrict__ elk,
    const int* __restrict__ sids, const int* __restrict__ cids,
    const float* __restrict__ w_meas, const float* __restrict__ w_event,
    const float* __restrict__ w_leak, const float* __restrict__ w_el,
    const float* __restrict__ b_meas, const float* __restrict__ b_event,
    const float* __restrict__ b_leak, const float* __restrict__ b_el,
    const float* __restrict__ stab_table, const float* __restrict__ cycle_table,
    const float* __restrict__ g1, const float* __restrict__ be1,
    const float* __restrict__ b11, const float* __restrict__ b12,
    const float* __restrict__ g2, const float* __restrict__ be2,
    const float* __restrict__ b21, const float* __restrict__ b22,
    float* __restrict__ out)
{
    __shared__ __align__(16) short Abuf[2][4 * 8 * 64 * 8];  // 2 x 32 KB (per tile)
    __shared__ float par[8 * 256];                           // 8 KB staged params
    // per-tile: [0..383] rowf[4][64]+rowi[2][64]; [384..1151] redp[64][12]
    // (redp no longer overlays rowf: embed-reads and lnred-writes share a slot)
    __shared__ __align__(16) float ubuf[2][1152];

    const int tid = threadIdx.x;
    const int w = tid >> 6;                 // 0..7
    const int half = w >> 2;                // tile id: 0 = waves 0-3, 1 = waves 4-7
    const int wh = w & 3;                   // wave-in-tile
    const int lane = tid & 63;
    const int q = lane >> 4, c = lane & 15;
    const int gl = (lane >> 2) | ((lane & 3) << 4);   // A read slot
    const int R0h = blockIdx.x * 2 * TT + half * TT;  // this tile's token base

    float (*rowf)[TT] = (float (*)[TT])ubuf[half];           // [4][64]
    int   (*rowi)[TT] = (int (*)[TT])(ubuf[half] + 256);     // [2][64]
    float *redp = ubuf[half] + 384;                          // [64][12]
    short *Ah = Abuf[half];

    // embed params direct from global (1 KB vectors, L2-hot); issued before
    // the first barrier so latency hides under staging. Dead after embed.
    float wm[4], we[4], wl[4], w2[4], bs[4];
    #pragma unroll
    for (int ntl = 0; ntl < 4; ++ntl) {
        int n = wh * 64 + ntl * 16 + c;
        wm[ntl] = w_meas[n];
        we[ntl] = w_event[n];
        wl[ntl] = w_leak[n];
        w2[ntl] = w_el[n];
        bs[ntl] = b_meas[n] + b_event[n] + b_leak[n] + b_el[n];
    }

    // ---- s1: stage ----
    // par rows: 0:g1 1:gW1 2:beW1 3:b12 4:g2 5:gW2 6:beW2 7:b22
    if (tid < 256) {
        int n = tid;
        par[0 * 256 + n] = g1[n];
        par[1 * 256 + n] = g_par[0 * 256 + n];
        par[2 * 256 + n] = g_par[1 * 256 + n];
        par[3 * 256 + n] = b12[n];
        par[4 * 256 + n] = g2[n];
        par[5 * 256 + n] = g_par[2 * 256 + n];
        par[6 * 256 + n] = g_par[3 * 256 + n];
        par[7 * 256 + n] = b22[n];
    }
    {
        int th = tid & 255;                  // thread index within tile
        if (th < TT) {
            rowf[0][th] = meas[R0h + th];
            rowf[1][th] = event[R0h + th];
            rowf[2][th] = leak[R0h + th];
            rowf[3][th] = elk[R0h + th];
            rowi[0][th] = sids[R0h + th];
            rowi[1][th] = cids[R0h + th];
        }
    }
    __syncthreads();   // barrier 1

    // ---- s2: embed (both tiles) ----
    float xr[4][4][4];
    #pragma unroll
    for (int rg = 0; rg < 4; ++rg)
        #pragma unroll
        for (int reg = 0; reg < 4; ++reg) {
            int m = rg * 16 + 4 * q + reg;
            float mv = rowf[0][m], ev = rowf[1][m], lv = rowf[2][m], e2 = rowf[3][m];
            const float* srow = stab_table + rowi[0][m] * 256;
            const float* crow = cycle_table + rowi[1][m] * 256;
            #pragma unroll
            for (int ntl = 0; ntl < 4; ++ntl) {
                int n = wh * 64 + ntl * 16 + c;
                xr[rg][ntl][reg] = mv * wm[ntl] + ev * we[ntl] + lv * wl[ntl]
                                 + e2 * w2[ntl] + bs[ntl] + srow[n] + crow[n];
            }
        }

    float4v acc[4][4];

    // A-write (x*g, un-normalized) + LN partial reduce in ONE slot — the GEMM
    // depends only on the A-writes; the shfl chain feeds the (later) U-phase.
    auto aw_write = [&](const float* g) {
        float gv[4];
        #pragma unroll
        for (int ntl = 0; ntl < 4; ++ntl)
            gv[ntl] = g[wh * 64 + ntl * 16 + c];
        #pragma unroll
        for (int rg = 0; rg < 4; ++rg)
            #pragma unroll
            for (int reg = 0; reg < 4; ++reg) {
                int m = rg * 16 + 4 * q + reg;
                #pragma unroll
                for (int ntl = 0; ntl < 4; ++ntl) {
                    int n = wh * 64 + ntl * 16 + c;
                    Ah[aidx(m, n)] = f2bf(xr[rg][ntl][reg] * gv[ntl]);
                }
            }
        // LN partial sums -> redp
        #pragma unroll
        for (int rg = 0; rg < 4; ++rg)
            #pragma unroll
            for (int reg = 0; reg < 4; ++reg) {
                float a = 0.f, b = 0.f;
                #pragma unroll
                for (int ntl = 0; ntl < 4; ++ntl) {
                    float v = xr[rg][ntl][reg];
                    a += v; b += v * v;
                }
                #pragma unroll
                for (int d = 1; d < 16; d <<= 1) {
                    a += __shfl_xor(a, d, 64);
                    b += __shfl_xor(b, d, 64);
                }
                if (c == 0) {
                    int m = rg * 16 + 4 * q + reg;
                    redp[m * 12 + wh] = a;
                    redp[m * 12 + 4 + wh] = b;
                }
            }
    };

    // U-phase: derive mu/rs from redp, apply folded-LN epilogue + gelu, write A.
    auto u_write = [&](const float* gw, const float* bw) {
        float gwv[4], bwv[4];
        #pragma unroll
        for (int ntl = 0; ntl < 4; ++ntl) {
            int n = wh * 64 + ntl * 16 + c;
            gwv[ntl] = gw[n]; bwv[ntl] = bw[n];
        }
        #pragma unroll
        for (int rg = 0; rg < 4; ++rg)
            #pragma unroll
            for (int reg = 0; reg < 4; ++reg) {
                int m = rg * 16 + 4 * q + reg;
                float4v a4 = *(const float4v*)&redp[m * 12];
                float4v b4 = *(const float4v*)&redp[m * 12 + 4];
                float a = a4[0] + a4[1] + a4[2] + a4[3];
                float b = b4[0] + b4[1] + b4[2] + b4[3];
                float mu = a * (1.0f / 256.0f);
                float ve = b * (1.0f / 256.0f) - mu * mu + EPS;
                float rs;
                asm("v_rsq_f32 %0, %1" : "=v"(rs) : "v"(ve));
                #pragma unroll
                for (int ntl = 0; ntl < 4; ++ntl) {
                    int n = wh * 64 + ntl * 16 + c;
                    float h = rs * (acc[rg][ntl][reg] - mu * gwv[ntl]) + bwv[ntl];
                    Ah[aidx(m, n)] = f2bf(gelu_erf(h));
                }
            }
    };

    short8 bh0[4];
    auto preB = [&](int g4) {
        const short* W = g_Wp + g4 * 65536;
        #pragma unroll
        for (int ntl = 0; ntl < 4; ++ntl) {
            int nt = wh * 4 + ntl;
            bh0[ntl] = *(const short8*)&W[((nt * 8 + 0) * 64 + lane) * 8];
        }
    };

    auto do_gemm = [&](int g4) {
        const short* W = g_Wp + g4 * 65536;
        #pragma unroll
        for (int rg = 0; rg < 4; ++rg)
            #pragma unroll
            for (int ntl = 0; ntl < 4; ++ntl)
                acc[rg][ntl] = (float4v){0.f, 0.f, 0.f, 0.f};
        short8 ah[2][4], bh[2][4];
        #pragma unroll
        for (int rg = 0; rg < 4; ++rg)
            ah[0][rg] = *(const short8*)&Ah[((rg * 8 + 0) * 64 + gl) * 8];
        #pragma unroll
        for (int ntl = 0; ntl < 4; ++ntl)
            bh[0][ntl] = bh0[ntl];
        #pragma unroll
        for (int kb = 0; kb < 8; ++kb) {
            const int cur = kb & 1, nxt = cur ^ 1;
            if (kb < 7) {
                #pragma unroll
                for (int rg = 0; rg < 4; ++rg)
                    ah[nxt][rg] = *(const short8*)&Ah[((rg * 8 + kb + 1) * 64 + gl) * 8];
                #pragma unroll
                for (int ntl = 0; ntl < 4; ++ntl) {
                    int nt = wh * 4 + ntl;
                    bh[nxt][ntl] = *(const short8*)&W[((nt * 8 + kb + 1) * 64 + lane) * 8];
                }
            }
            __builtin_amdgcn_s_setprio(1);
            #pragma unroll
            for (int rg = 0; rg < 4; ++rg)
                #pragma unroll
                for (int ntl = 0; ntl < 4; ++ntl)
                    acc[rg][ntl] = __builtin_amdgcn_mfma_f32_16x16x32_bf16(
                        ah[cur][rg], bh[cur][ntl], acc[rg][ntl], 0, 0, 0);
            __builtin_amdgcn_s_setprio(0);
        }
    };

    auto resadd = [&]() {
        float bv[4];
        #pragma unroll
        for (int ntl = 0; ntl < 4; ++ntl)
            bv[ntl] = par[3 * 256 + wh * 64 + ntl * 16 + c];
        #pragma unroll
        for (int rg = 0; rg < 4; ++rg)
            #pragma unroll
            for (int ntl = 0; ntl < 4; ++ntl)
                #pragma unroll
                for (int reg = 0; reg < 4; ++reg)
                    xr[rg][ntl][reg] += acc[rg][ntl][reg] + bv[ntl];
    };

    auto store_out = [&]() {
        float bv[4];
        #pragma unroll
        for (int ntl = 0; ntl < 4; ++ntl)
            bv[ntl] = par[7 * 256 + wh * 64 + ntl * 16 + c];
        #pragma unroll
        for (int rg = 0; rg < 4; ++rg)
            #pragma unroll
            for (int ntl = 0; ntl < 4; ++ntl)
                #pragma unroll
                for (int reg = 0; reg < 4; ++reg) {
                    int m = rg * 16 + 4 * q + reg;
                    int n = wh * 64 + ntl * 16 + c;
                    out[(size_t)(R0h + m) * 256 + n] =
                        xr[rg][ntl][reg] + acc[rg][ntl][reg] + bv[ntl];
                }
    };

    // ---- anti-phase schedule (10 barriers incl. stage) ----
    // s2 tail: A does AW1 in the embed slot (redp disjoint from rowf now)
    if (!half) { preB(0); aw_write(par + 0 * 256); }
    __syncthreads();   // 2
    // s3: A:G1      B:AW1
    if (!half) do_gemm(0); else { preB(0); aw_write(par + 0 * 256); }
    __syncthreads();   // 3
    // s4: A:U1      B:G1
    if (!half) { preB(1); u_write(par + 1 * 256, par + 2 * 256); } else do_gemm(0);
    __syncthreads();   // 4
    // s5: A:G2      B:U1
    if (!half) do_gemm(1); else { preB(1); u_write(par + 1 * 256, par + 2 * 256); }
    __syncthreads();   // 5
    // s6: A:[R;AW2] B:G2
    if (!half) { preB(2); resadd(); aw_write(par + 4 * 256); } else do_gemm(1);
    __syncthreads();   // 6
    // s7: A:G3      B:[R;AW2]
    if (!half) do_gemm(2); else { preB(2); resadd(); aw_write(par + 4 * 256); }
    __syncthreads();   // 7
    // s8: A:U2      B:G3
    if (!half) { preB(3); u_write(par + 5 * 256, par + 6 * 256); } else do_gemm(2);
    __syncthreads();   // 8
    // s9: A:G4      B:U2
    if (!half) do_gemm(3); else { preB(3); u_write(par + 5 * 256, par + 6 * 256); }
    __syncthreads();   // 9
    // s10: A:S      B:G4
    if (!half) store_out(); else do_gemm(3);
    // s11: B:S (no barrier: stores independent)
    if (half) store_out();
}

extern "C" void kernel_launch(void* const* d_in, const int* in_sizes, int n_in,
                              void* d_out, int out_size, void* d_ws, size_t ws_size,
                              hipStream_t stream) {
    pack_w<<<1024, 256, 0, stream>>>(
        (const float*)d_in[18], (const float*)d_in[20],
        (const float*)d_in[24], (const float*)d_in[26]);
    prep_par<<<4, 256, 0, stream>>>(
        (const float*)d_in[16], (const float*)d_in[17],
        (const float*)d_in[19], (const float*)d_in[18],
        (const float*)d_in[22], (const float*)d_in[23],
        (const float*)d_in[25], (const float*)d_in[24]);
    fused_kernel<<<NTOK / (2 * TT), 512, 0, stream>>>(
        (const float*)d_in[0], (const float*)d_in[1],
        (const float*)d_in[2], (const float*)d_in[3],
        (const int*)d_in[4], (const int*)d_in[5],
        (const float*)d_in[6], (const float*)d_in[8],
        (const float*)d_in[10], (const float*)d_in[12],
        (const float*)d_in[7], (const float*)d_in[9],
        (const float*)d_in[11], (const float*)d_in[13],
        (const float*)d_in[14], (const float*)d_in[15],
        (const float*)d_in[16], (const float*)d_in[17],
        (const float*)d_in[19], (const float*)d_in[21],
        (const float*)d_in[22], (const float*)d_in[23],
        (const float*)d_in[25], (const float*)d_in[27],
        (float*)d_out);
}

// Round 15
// 588.550 us; speedup vs baseline: 1.1197x; 1.1197x over previous
//
#include <hip/hip_runtime.h>

#define NTOK 262144
#define TT 64
#define EPS 1e-5f

typedef short short8 __attribute__((ext_vector_type(8)));
typedef float float4v __attribute__((ext_vector_type(4)));

// Packed bf16 weights: [g(4)][nt(16)][kb(8)][lane(64)][j(8)]
// element = W[kb*32 + (lane>>4)*8 + j][nt*16 + (lane&15)]
__device__ __align__(16) short g_Wp[4 * 65536];   // 512 KB static device mem

__device__ __forceinline__ short f2bf(float f) {   // RTN f32->bf16
    uint32_t u = __builtin_bit_cast(uint32_t, f);
    u += 0x7FFFu + ((u >> 16) & 1u);
    return (short)(u >> 16);
}

__global__ void pack_w(const float* __restrict__ W11, const float* __restrict__ W12,
                       const float* __restrict__ W21, const float* __restrict__ W22) {
    int t = blockIdx.x * 256 + threadIdx.x;          // 0 .. 262143
    int g = t >> 16;
    int r = t & 65535;
    int j = r & 7, l = (r >> 3) & 63, kb = (r >> 9) & 7, nt = (r >> 12) & 15;
    int n = nt * 16 + (l & 15);
    int k = kb * 32 + (l >> 4) * 8 + j;
    const float* W = (g == 0) ? W11 : (g == 1) ? W12 : (g == 2) ? W21 : W22;
    g_Wp[t] = f2bf(W[k * 256 + n]);
}

// exact-erf gelu via Abramowitz-Stegun 7.1.26 (max erf err 1.5e-7).
__device__ __forceinline__ float gelu_erf(float v) {
    float z = fabsf(v) * 0.70710678118654752f;
    float d = __builtin_fmaf(0.3275911f, z, 1.0f);
    float t;
    asm("v_rcp_f32 %0, %1" : "=v"(t) : "v"(d));
    float poly = t * (0.254829592f + t * (-0.284496736f + t * (1.421413741f
               + t * (-1.453152027f + t * 1.061405429f))));
    float er = 1.0f - poly * __expf(-z * z);
    er = copysignf(er, v);
    return 0.5f * v * (1.0f + er);
}

// VALU-pipe cross-lane add via DPP (replaces ds_swizzle shfl_xor: the LDS
// pipe is shared per-CU across 8 waves and is ~co-equal with VALU as the
// busiest resource; DPP adds run on the VALU pipe instead).
// 4-step 16-lane reduce: quad_perm(1,0,3,2)=xor1, quad_perm(2,3,0,1)=xor2,
// row_half_mirror pairs quads in each oct, row_mirror pairs octs in the 16.
template <int CTRL>
__device__ __forceinline__ float dpp_add(float v) {
    int vi = __builtin_bit_cast(int, v);
    int other = __builtin_amdgcn_update_dpp(0, vi, CTRL, 0xF, 0xF, true);
    return v + __builtin_bit_cast(float, other);
}
__device__ __forceinline__ float red16(float v) {
    v = dpp_add<0xB1>(v);    // quad_perm(1,0,3,2)  : + lane^1
    v = dpp_add<0x4E>(v);    // quad_perm(2,3,0,1)  : + lane^2
    v = dpp_add<0x141>(v);   // row_half_mirror     : + other quad of oct
    v = dpp_add<0x140>(v);   // row_mirror          : + other oct of 16-row
    return v;
}

// A-operand packed LDS index for element (m, k), rotr2 lane-slot swizzle.
// ds_write_b16 bank = 4q + 16*(c>>3) + ((c&7)>>1): 2 lanes/bank (free, m136).
__device__ __forceinline__ int aidx(int m, int k) {
    int lp = (m & 15) | (((k >> 3) & 3) << 4);
    int gs = (lp >> 2) | ((lp & 3) << 4);
    return ((((m >> 4) * 8 + (k >> 5)) * 64) + gs) * 8 + (k & 7);
}

// Dual-tile anti-phase pipeline: 512 threads = 2 x (4 waves, 64 tokens).
// Tile B runs one sub-phase behind tile A. Measured evidence:
//  r5/r7: this 13-slot schedule = 367 µs (best);
//  r12: merging LN into fewer, heavier slots (10 barriers) = 403 µs —
//  slot BALANCE beats barrier count; keep the 13-slot pairing.
// NOTE: do NOT force a waves/EU bound: (256,2) and (512,4) both produced
// wrong results (forced register-cap codegen). (512,1) leaves the allocator
// free and has been correct in every measured round.
__global__ __launch_bounds__(512, 1) void fused_kernel(
    const float* __restrict__ meas, const float* __restrict__ event,
    const float* __restrict__ leak, const float* __restrict__ elk,
    const int* __restrict__ sids, const int* __restrict__ cids,
    const float* __restrict__ w_meas, const float* __restrict__ w_event,
    const float* __restrict__ w_leak, const float* __restrict__ w_el,
    const float* __restrict__ b_meas, const float* __restrict__ b_event,
    const float* __restrict__ b_leak, const float* __restrict__ b_el,
    const float* __restrict__ stab_table, const float* __restrict__ cycle_table,
    const float* __restrict__ g1, const float* __restrict__ be1,
    const float* __restrict__ b11, const float* __restrict__ b12,
    const float* __restrict__ g2, const float* __restrict__ be2,
    const float* __restrict__ b21, const float* __restrict__ b22,
    float* __restrict__ out)
{
    __shared__ __align__(16) short Abuf[2][4 * 8 * 64 * 8];  // 2 x 32 KB (per tile)
    __shared__ float par[8 * 256];                           // 8 KB staged params
    __shared__ __align__(16) float ubuf[2][768];             // per-tile overlay

    const int tid = threadIdx.x;
    const int w = tid >> 6;                 // 0..7
    const int half = w >> 2;                // tile id: 0 = waves 0-3, 1 = waves 4-7
    const int wh = w & 3;                   // wave-in-tile
    const int lane = tid & 63;
    const int q = lane >> 4, c = lane & 15;
    const int gl = (lane >> 2) | ((lane & 3) << 4);   // A read slot
    const int R0h = blockIdx.x * 2 * TT + half * TT;  // this tile's token base

    float (*rowf)[TT] = (float (*)[TT])ubuf[half];           // [4][64]
    int   (*rowi)[TT] = (int (*)[TT])(ubuf[half] + 256);     // [2][64]
    float *redp = ubuf[half];                                // [64][12]
    short *Ah = Abuf[half];

    // embed params direct from global (1 KB vectors, L2-hot); issued before
    // the first barrier so latency hides under staging. Dead after embed.
    float wm[4], we[4], wl[4], w2[4], bs[4];
    #pragma unroll
    for (int ntl = 0; ntl < 4; ++ntl) {
        int n = wh * 64 + ntl * 16 + c;
        wm[ntl] = w_meas[n];
        we[ntl] = w_event[n];
        wl[ntl] = w_leak[n];
        w2[ntl] = w_el[n];
        bs[ntl] = b_meas[n] + b_event[n] + b_leak[n] + b_el[n];
    }

    // ---- s1: stage ----
    // par rows: 0:g1 1:be1 2:b11 3:b12 4:g2 5:be2 6:b21 7:b22
    if (tid < 256) {
        int n = tid;
        par[0 * 256 + n] = g1[n];
        par[1 * 256 + n] = be1[n];
        par[2 * 256 + n] = b11[n];
        par[3 * 256 + n] = b12[n];
        par[4 * 256 + n] = g2[n];
        par[5 * 256 + n] = be2[n];
        par[6 * 256 + n] = b21[n];
        par[7 * 256 + n] = b22[n];
    }
    {
        int th = tid & 255;                  // thread index within tile
        if (th < TT) {
            rowf[0][th] = meas[R0h + th];
            rowf[1][th] = event[R0h + th];
            rowf[2][th] = leak[R0h + th];
            rowf[3][th] = elk[R0h + th];
            rowi[0][th] = sids[R0h + th];
            rowi[1][th] = cids[R0h + th];
        }
    }
    __syncthreads();

    // ---- s2: embed (both tiles) ----
    // xr element: row m = rg*16 + 4*q + reg, col n = wh*64 + ntl*16 + c
    float xr[4][4][4];
    #pragma unroll
    for (int rg = 0; rg < 4; ++rg)
        #pragma unroll
        for (int reg = 0; reg < 4; ++reg) {
            int m = rg * 16 + 4 * q + reg;
            float mv = rowf[0][m], ev = rowf[1][m], lv = rowf[2][m], e2 = rowf[3][m];
            const float* srow = stab_table + rowi[0][m] * 256;
            const float* crow = cycle_table + rowi[1][m] * 256;
            #pragma unroll
            for (int ntl = 0; ntl < 4; ++ntl) {
                int n = wh * 64 + ntl * 16 + c;
                xr[rg][ntl][reg] = mv * wm[ntl] + ev * we[ntl] + lv * wl[ntl]
                                 + e2 * w2[ntl] + bs[ntl] + srow[n] + crow[n];
            }
        }
    __syncthreads();   // rowf/rowi reads done before redp overlay writes

    float4v acc[4][4];

    auto ln_reduce = [&]() {
        float s[4][4], s2[4][4];
        #pragma unroll
        for (int rg = 0; rg < 4; ++rg)
            #pragma unroll
            for (int reg = 0; reg < 4; ++reg) {
                float a = 0.f, b = 0.f;
                #pragma unroll
                for (int ntl = 0; ntl < 4; ++ntl) {
                    float v = xr[rg][ntl][reg];
                    a += v; b += v * v;
                }
                // 16-lane reduce on the VALU pipe (DPP), not the DS pipe.
                a = red16(a);
                b = red16(b);
                s[rg][reg] = a; s2[rg][reg] = b;
            }
        if (c == 0) {
            #pragma unroll
            for (int rg = 0; rg < 4; ++rg)
                #pragma unroll
                for (int reg = 0; reg < 4; ++reg) {
                    int m = rg * 16 + 4 * q + reg;
                    redp[m * 12 + wh] = s[rg][reg];
                    redp[m * 12 + 4 + wh] = s2[rg][reg];
                }
        }
    };

    auto ln_write = [&](const float* g, const float* be) {
        float gv[4], bv[4];
        #pragma unroll
        for (int ntl = 0; ntl < 4; ++ntl) {
            int n = wh * 64 + ntl * 16 + c;
            gv[ntl] = g[n]; bv[ntl] = be[n];
        }
        #pragma unroll
        for (int rg = 0; rg < 4; ++rg)
            #pragma unroll
            for (int reg = 0; reg < 4; ++reg) {
                int m = rg * 16 + 4 * q + reg;
                float4v a4 = *(const float4v*)&redp[m * 12];
                float4v b4 = *(const float4v*)&redp[m * 12 + 4];
                float a = a4[0] + a4[1] + a4[2] + a4[3];
                float b = b4[0] + b4[1] + b4[2] + b4[3];
                float mu = a * (1.0f / 256.0f);
                float ve = b * (1.0f / 256.0f) - mu * mu + EPS;
                float rs;
                asm("v_rsq_f32 %0, %1" : "=v"(rs) : "v"(ve));
                #pragma unroll
                for (int ntl = 0; ntl < 4; ++ntl) {
                    int n = wh * 64 + ntl * 16 + c;
                    Ah[aidx(m, n)] = f2bf((xr[rg][ntl][reg] - mu) * rs * gv[ntl] + bv[ntl]);
                }
            }
    };

    short8 bh0[4];
    auto preB = [&](int g4) {
        const short* W = g_Wp + g4 * 65536;
        #pragma unroll
        for (int ntl = 0; ntl < 4; ++ntl) {
            int nt = wh * 4 + ntl;
            bh0[ntl] = *(const short8*)&W[((nt * 8 + 0) * 64 + lane) * 8];
        }
    };

    auto do_gemm = [&](int g4) {
        const short* W = g_Wp + g4 * 65536;
        #pragma unroll
        for (int rg = 0; rg < 4; ++rg)
            #pragma unroll
            for (int ntl = 0; ntl < 4; ++ntl)
                acc[rg][ntl] = (float4v){0.f, 0.f, 0.f, 0.f};
        short8 ah[2][4], bh[2][4];
        #pragma unroll
        for (int rg = 0; rg < 4; ++rg)
            ah[0][rg] = *(const short8*)&Ah[((rg * 8 + 0) * 64 + gl) * 8];
        #pragma unroll
        for (int ntl = 0; ntl < 4; ++ntl)
            bh[0][ntl] = bh0[ntl];
        #pragma unroll
        for (int kb = 0; kb < 8; ++kb) {
            const int cur = kb & 1, nxt = cur ^ 1;
            if (kb < 7) {
                #pragma unroll
                for (int rg = 0; rg < 4; ++rg)
                    ah[nxt][rg] = *(const short8*)&Ah[((rg * 8 + kb + 1) * 64 + gl) * 8];
                #pragma unroll
                for (int ntl = 0; ntl < 4; ++ntl) {
                    int nt = wh * 4 + ntl;
                    bh[nxt][ntl] = *(const short8*)&W[((nt * 8 + kb + 1) * 64 + lane) * 8];
                }
            }
            __builtin_amdgcn_s_setprio(1);
            #pragma unroll
            for (int rg = 0; rg < 4; ++rg)
                #pragma unroll
                for (int ntl = 0; ntl < 4; ++ntl)
                    acc[rg][ntl] = __builtin_amdgcn_mfma_f32_16x16x32_bf16(
                        ah[cur][rg], bh[cur][ntl], acc[rg][ntl], 0, 0, 0);
            __builtin_amdgcn_s_setprio(0);
        }
    };

    auto gelu_write = [&](const float* bias) {
        float bv[4];
        #pragma unroll
        for (int ntl = 0; ntl < 4; ++ntl)
            bv[ntl] = bias[wh * 64 + ntl * 16 + c];
        #pragma unroll
        for (int rg = 0; rg < 4; ++rg)
            #pragma unroll
            for (int ntl = 0; ntl < 4; ++ntl)
                #pragma unroll
                for (int reg = 0; reg < 4; ++reg) {
                    int m = rg * 16 + 4 * q + reg;
                    int n = wh * 64 + ntl * 16 + c;
                    Ah[aidx(m, n)] = f2bf(gelu_erf(acc[rg][ntl][reg] + bv[ntl]));
                }
    };

    auto resadd = [&]() {
        float bv[4];
        #pragma unroll
        for (int ntl = 0; ntl < 4; ++ntl)
            bv[ntl] = par[3 * 256 + wh * 64 + ntl * 16 + c];
        #pragma unroll
        for (int rg = 0; rg < 4; ++rg)
            #pragma unroll
            for (int ntl = 0; ntl < 4; ++ntl)
                #pragma unroll
                for (int reg = 0; reg < 4; ++reg)
                    xr[rg][ntl][reg] += acc[rg][ntl][reg] + bv[ntl];
    };

    auto store_out = [&]() {
        float bv[4];
        #pragma unroll
        for (int ntl = 0; ntl < 4; ++ntl)
            bv[ntl] = par[7 * 256 + wh * 64 + ntl * 16 + c];
        #pragma unroll
        for (int rg = 0; rg < 4; ++rg)
            #pragma unroll
            for (int ntl = 0; ntl < 4; ++ntl)
                #pragma unroll
                for (int reg = 0; reg < 4; ++reg) {
                    int m = rg * 16 + 4 * q + reg;
                    int n = wh * 64 + ntl * 16 + c;
                    out[(size_t)(R0h + m) * 256 + n] =
                        xr[rg][ntl][reg] + acc[rg][ntl][reg] + bv[ntl];
                }
    };

    // ---- anti-phase schedule: tile A (half==0) leads by one sub-phase ----
    // s3
    if (!half) ln_reduce();
    __syncthreads();
    // s4: A:lnwr1  B:lnred1
    if (!half) { preB(0); ln_write(par + 0 * 256, par + 1 * 256); } else ln_reduce();
    __syncthreads();
    // s5: A:G1     B:lnwr1
    if (!half) do_gemm(0); else { preB(0); ln_write(par + 0 * 256, par + 1 * 256); }
    __syncthreads();
    // s6: A:U1     B:G1
    if (!half) { preB(1); gelu_write(par + 2 * 256); } else do_gemm(0);
    __syncthreads();
    // s7: A:G2     B:U1
    if (!half) do_gemm(1); else { preB(1); gelu_write(par + 2 * 256); }
    __syncthreads();
    // s8: A:R      B:G2
    if (!half) resadd(); else do_gemm(1);
    __syncthreads();
    // s9: A:lnred2 B:R
    if (!half) ln_reduce(); else resadd();
    __syncthreads();
    // s10: A:lnwr2 B:lnred2
    if (!half) { preB(2); ln_write(par + 4 * 256, par + 5 * 256); } else ln_reduce();
    __syncthreads();
    // s11: A:G3    B:lnwr2
    if (!half) do_gemm(2); else { preB(2); ln_write(par + 4 * 256, par + 5 * 256); }
    __syncthreads();
    // s12: A:U2    B:G3
    if (!half) { preB(3); gelu_write(par + 6 * 256); } else do_gemm(2);
    __syncthreads();
    // s13: A:G4    B:U2
    if (!half) do_gemm(3); else { preB(3); gelu_write(par + 6 * 256); }
    __syncthreads();
    // s14: A:S     B:G4
    if (!half) store_out(); else do_gemm(3);
    // s15: B:S  (no barrier needed: stores are independent)
    if (half) store_out();
}

extern "C" void kernel_launch(void* const* d_in, const int* in_sizes, int n_in,
                              void* d_out, int out_size, void* d_ws, size_t ws_size,
                              hipStream_t stream) {
    pack_w<<<1024, 256, 0, stream>>>(
        (const float*)d_in[18], (const float*)d_in[20],
        (const float*)d_in[24], (const float*)d_in[26]);
    fused_kernel<<<NTOK / (2 * TT), 512, 0, stream>>>(
        (const float*)d_in[0], (const float*)d_in[1],
        (const float*)d_in[2], (const float*)d_in[3],
        (const int*)d_in[4], (const int*)d_in[5],
        (const float*)d_in[6], (const float*)d_in[8],
        (const float*)d_in[10], (const float*)d_in[12],
        (const float*)d_in[7], (const float*)d_in[9],
        (const float*)d_in[11], (const float*)d_in[13],
        (const float*)d_in[14], (const float*)d_in[15],
        (const float*)d_in[16], (const float*)d_in[17],
        (const float*)d_in[19], (const float*)d_in[21],
        (const float*)d_in[22], (const float*)d_in[23],
        (const float*)d_in[25], (const float*)d_in[27],
        (float*)d_out);
}